// Round 1
// baseline (102.924 us; speedup 1.0000x reference)
//
#include <hip/hip_runtime.h>
#include <cstdint>
#include <cstddef>

typedef __bf16 bf16x8 __attribute__((ext_vector_type(8)));
typedef float f32x4 __attribute__((ext_vector_type(4)));
typedef unsigned short u16x4 __attribute__((ext_vector_type(4)));
typedef unsigned short u16x8 __attribute__((ext_vector_type(8)));

#define MFMA16(a, b, c) __builtin_amdgcn_mfma_f32_16x16x32_bf16(a, b, c, 0, 0, 0)

__device__ __forceinline__ unsigned short f2bf(float f) {
    unsigned u = __builtin_bit_cast(unsigned, f);
    u = (u + 0x7FFFu + ((u >> 16) & 1u)) >> 16;   // RNE
    return (unsigned short)u;
}

// ---------------------------------------------------------------- posenc table
__global__ void pe_fill(float* __restrict__ pe) {
    int n = blockIdx.x;          // 0..1023
    int d = threadIdx.x;         // 0..255
    int j = d >> 1;
    float div = expf(-(float)(2 * j) * 0.03597789207808881f);  // ln(10000)/256
    float ang = (float)n * div;
    pe[n * 256 + d] = (d & 1) ? cosf(ang) : sinf(ang);
}

// ---------------------------------------------------------------- patch embed
struct EmbedArgs {
    const float* src;
    const float* W;      // (256, 768) row-major: W[d][k]
    const float* bias;   // (256,)
    const float* pe;     // (1024, 256)
    unsigned short* dst; // bf16 out
    int Np, lgNp, G, lgG, imgS, trans;
};

// E[m][d] = sum_k patch[m][k] * W[d][k] + bias[d] + pe[n][d]
// tile M=128 x N=256, BK=32, 512 threads = 8 waves (2x4), wave = 64x64
__global__ __launch_bounds__(512)
void embed_all(EmbedArgs A0, EmbedArgs A1, EmbedArgs A2, EmbedArgs A3) {
    __shared__ unsigned short As[128][40];   // +8 pad -> 80B stride (16B aligned)
    __shared__ unsigned short Bs[256][40];

    const int bx = blockIdx.x;
    EmbedArgs A;
    if      (bx < 128) A = A0;
    else if (bx < 256) A = A1;
    else if (bx < 384) A = A2;
    else               A = A3;
    const int m0 = (bx & 127) * 128;

    const int t = threadIdx.x;
    const int lane = t & 63, wid = t >> 6;
    const int wr = wid >> 2, wc = wid & 3;
    const int l15 = lane & 15, l4 = lane >> 4;

    int arow[2], akq[2];
    const float* abase[2];
#pragma unroll
    for (int i = 0; i < 2; ++i) {
        int f = t + i * 512;          // 1024 float4 for the 128x32 A tile
        arow[i] = f >> 3;
        akq[i] = (f & 7) * 4;
        int m = m0 + arow[i];
        int b = m >> A.lgNp, n = m & (A.Np - 1);
        int gy = n >> A.lgG, gx = n & (A.G - 1);
        abase[i] = A.src + ((size_t)(b * 3) * A.imgS + gy * 16) * (size_t)A.imgS + gx * 16;
    }
    int bcol[4], bkq[4];
#pragma unroll
    for (int i = 0; i < 4; ++i) {
        int f = t + i * 512;          // 2048 float4 for the 256x32 B tile
        bcol[i] = f >> 3;
        bkq[i] = (f & 7) * 4;
    }

    f32x4 acc[4][4];
#pragma unroll
    for (int i = 0; i < 4; ++i)
#pragma unroll
        for (int j = 0; j < 4; ++j) acc[i][j] = f32x4{0.f, 0.f, 0.f, 0.f};

    for (int k0 = 0; k0 < 768; k0 += 32) {
        f32x4 av[2], bv[4];
#pragma unroll
        for (int i = 0; i < 2; ++i) {
            int k = k0 + akq[i];
            int c = k >> 8, py = (k >> 4) & 15, px = k & 15;
            av[i] = *(const f32x4*)(abase[i] + ((size_t)c * A.imgS + py) * (size_t)A.imgS + px);
        }
#pragma unroll
        for (int i = 0; i < 4; ++i)
            bv[i] = *(const f32x4*)(A.W + (size_t)bcol[i] * 768 + k0 + bkq[i]);

        __syncthreads();
#pragma unroll
        for (int i = 0; i < 2; ++i) {
            u16x4 o;
#pragma unroll
            for (int j = 0; j < 4; ++j) o[j] = f2bf(av[i][j]);
            *(u16x4*)&As[arow[i]][akq[i]] = o;
        }
#pragma unroll
        for (int i = 0; i < 4; ++i) {
            u16x4 o;
#pragma unroll
            for (int j = 0; j < 4; ++j) o[j] = f2bf(bv[i][j]);
            *(u16x4*)&Bs[bcol[i]][bkq[i]] = o;
        }
        __syncthreads();

        bf16x8 af[4], bfr[4];
#pragma unroll
        for (int m16 = 0; m16 < 4; ++m16)
            af[m16] = *(const bf16x8*)&As[wr * 64 + m16 * 16 + l15][l4 * 8];
#pragma unroll
        for (int n16 = 0; n16 < 4; ++n16)
            bfr[n16] = *(const bf16x8*)&Bs[wc * 64 + n16 * 16 + l15][l4 * 8];
#pragma unroll
        for (int m16 = 0; m16 < 4; ++m16)
#pragma unroll
            for (int n16 = 0; n16 < 4; ++n16)
                acc[m16][n16] = MFMA16(af[m16], bfr[n16], acc[m16][n16]);
    }

#pragma unroll
    for (int m16 = 0; m16 < 4; ++m16) {
#pragma unroll
        for (int n16 = 0; n16 < 4; ++n16) {
            int d = wc * 64 + n16 * 16 + l15;
            int hh = d >> 5, hd = d & 31;
            float bsv = A.bias[d];
#pragma unroll
            for (int r = 0; r < 4; ++r) {
                int row = wr * 64 + m16 * 16 + l4 * 4 + r;
                int m = m0 + row;
                int b = m >> A.lgNp, n = m & (A.Np - 1);
                float v = acc[m16][n16][r] + bsv + A.pe[n * 256 + d];
                unsigned short bvv = f2bf(v);
                if (A.trans)
                    A.dst[(((size_t)(b * 8 + hh)) * 32 + hd) * (size_t)A.Np + n] = bvv;
                else
                    A.dst[(((size_t)(b * 8 + hh)) * (size_t)A.Np + n) * 32 + hd] = bvv;
            }
        }
    }
}

// ---------------------------------------------------------------- stage 2: Ks softmax + KV
__global__ __launch_bounds__(512)
void s2kv_kernel(const unsigned short* __restrict__ ah_ws,
                 const unsigned short* __restrict__ kh_ws,
                 const unsigned short* __restrict__ vT_ws,
                 unsigned short* __restrict__ kvT_ws) {
    __shared__ unsigned short ahs[128][40];
    __shared__ unsigned short khs[128][40];
    __shared__ unsigned short vts[32][136];  // 272B stride
    __shared__ unsigned short Ps[128][136];

    const int bid = blockIdx.x;
    const int half = bid & 1;
    const int h = (bid >> 1) & 7, b = bid >> 4;
    const int a0 = half * 128;
    const int t = threadIdx.x, lane = t & 63, wid = t >> 6;  // 8 waves x 16 rows
    const int l15 = lane & 15, l4 = lane >> 4;
    const size_t bh = (size_t)(b * 8 + h);

    const unsigned short* ahp = ah_ws + (bh * 256 + a0) * 32;
    const unsigned short* khp = kh_ws + bh * 1024 * 32;
    const unsigned short* vtp = vT_ws + bh * 32 * 1024;

    {
        int row = t >> 2, kq = (t & 3) * 8;
        *(u16x8*)&ahs[row][kq] = *(const u16x8*)(ahp + row * 32 + kq);
    }
    __syncthreads();
    const bf16x8 af = *(const bf16x8*)&ahs[wid * 16 + l15][l4 * 8];

    const float scale = 0.17677669529663687f;
    float rs[4] = {0.f, 0.f, 0.f, 0.f};
    const f32x4 z = {0.f, 0.f, 0.f, 0.f};
    f32x4 kv[2];
    kv[0] = z; kv[1] = z;

    for (int kt = 0; kt < 8; ++kt) {
        const int n0 = kt * 128;
        __syncthreads();
        {
            int row = t >> 2, kq = (t & 3) * 8;
            *(u16x8*)&khs[row][kq] = *(const u16x8*)(khp + (size_t)(n0 + row) * 32 + kq);
        }
        {
            int row = t >> 4, cq = (t & 15) * 8;
            *(u16x8*)&vts[row][cq] = *(const u16x8*)(vtp + (size_t)row * 1024 + n0 + cq);
        }
        __syncthreads();
#pragma unroll
        for (int n16 = 0; n16 < 8; ++n16) {
            bf16x8 bfr = *(const bf16x8*)&khs[n16 * 16 + l15][l4 * 8];
            f32x4 s = MFMA16(af, bfr, z);
#pragma unroll
            for (int r = 0; r < 4; ++r) {
                float e = __expf(s[r] * scale);
                rs[r] += e;
                Ps[wid * 16 + l4 * 4 + r][n16 * 16 + l15] = f2bf(e);
            }
        }
        __syncthreads();
#pragma unroll
        for (int ks = 0; ks < 4; ++ks) {
            bf16x8 pa = *(const bf16x8*)&Ps[wid * 16 + l15][ks * 32 + l4 * 8];
#pragma unroll
            for (int n16 = 0; n16 < 2; ++n16) {
                bf16x8 vb = *(const bf16x8*)&vts[n16 * 16 + l15][ks * 32 + l4 * 8];
                kv[n16] = MFMA16(pa, vb, kv[n16]);
            }
        }
    }
#pragma unroll
    for (int r = 0; r < 4; ++r) {
        rs[r] += __shfl_xor(rs[r], 1, 64);
        rs[r] += __shfl_xor(rs[r], 2, 64);
        rs[r] += __shfl_xor(rs[r], 4, 64);
        rs[r] += __shfl_xor(rs[r], 8, 64);
    }
#pragma unroll
    for (int n16 = 0; n16 < 2; ++n16)
#pragma unroll
        for (int r = 0; r < 4; ++r) {
            int m = a0 + wid * 16 + l4 * 4 + r;
            int d = n16 * 16 + l15;
            kvT_ws[bh * 8192 + (size_t)d * 256 + m] = f2bf(kv[n16][r] / rs[r]);
        }
}

// ---------------------------------------------------------------- stage 3: Qs softmax + A + unshuffle
__global__ __launch_bounds__(256)
void qsa_kernel(const unsigned short* __restrict__ qh_ws,
                const unsigned short* __restrict__ ah_ws,
                const unsigned short* __restrict__ kvT_ws,
                float* __restrict__ out) {
    __shared__ unsigned short qhs[64][40];
    __shared__ unsigned short ahs[256][40];
    __shared__ unsigned short kvt[32][264];  // 528B stride
    __shared__ unsigned short Ps[64][264];

    const int bid = blockIdx.x;
    const int qt = bid & 15, h = (bid >> 4) & 7, b = bid >> 7;
    const int m0 = qt * 64;
    const int t = threadIdx.x, lane = t & 63, wid = t >> 6;  // 4 waves x 16 rows
    const int l15 = lane & 15, l4 = lane >> 4;
    const size_t bh = (size_t)(b * 8 + h);

    const unsigned short* qhp = qh_ws + (bh * 1024 + m0) * 32;
    const unsigned short* ahp = ah_ws + bh * 256 * 32;

    {
        int row = t >> 2, kq = (t & 3) * 8;  // 64x32 = 2048
        *(u16x8*)&qhs[row][kq] = *(const u16x8*)(qhp + row * 32 + kq);
    }
    {
        *(u16x8*)&ahs[t][0]  = *(const u16x8*)(ahp + (size_t)t * 32);
        *(u16x8*)&ahs[t][8]  = *(const u16x8*)(ahp + (size_t)t * 32 + 8);
        *(u16x8*)&ahs[t][16] = *(const u16x8*)(ahp + (size_t)t * 32 + 16);
        *(u16x8*)&ahs[t][24] = *(const u16x8*)(ahp + (size_t)t * 32 + 24);
    }
#pragma unroll
    for (int i = 0; i < 4; ++i) {
        int chunk = t + i * 256;             // 1024 chunks of 8 elems
        int row = chunk >> 5, cq = (chunk & 31) * 8;
        *(u16x8*)&kvt[row][cq] = *(const u16x8*)(kvT_ws + bh * 8192 + (size_t)row * 256 + cq);
    }
    __syncthreads();

    const bf16x8 qa = *(const bf16x8*)&qhs[wid * 16 + l15][l4 * 8];
    const float scale = 0.17677669529663687f;
    const f32x4 z = {0.f, 0.f, 0.f, 0.f};
    float rs[4] = {0.f, 0.f, 0.f, 0.f};
#pragma unroll
    for (int n16 = 0; n16 < 16; ++n16) {
        bf16x8 bfr = *(const bf16x8*)&ahs[n16 * 16 + l15][l4 * 8];
        f32x4 s = MFMA16(qa, bfr, z);
#pragma unroll
        for (int r = 0; r < 4; ++r) {
            float e = __expf(s[r] * scale);
            rs[r] += e;
            Ps[wid * 16 + l4 * 4 + r][n16 * 16 + l15] = f2bf(e);
        }
    }
#pragma unroll
    for (int r = 0; r < 4; ++r) {
        rs[r] += __shfl_xor(rs[r], 1, 64);
        rs[r] += __shfl_xor(rs[r], 2, 64);
        rs[r] += __shfl_xor(rs[r], 4, 64);
        rs[r] += __shfl_xor(rs[r], 8, 64);
    }
    __syncthreads();

    f32x4 o[2];
    o[0] = z; o[1] = z;
#pragma unroll
    for (int ks = 0; ks < 8; ++ks) {
        bf16x8 pa = *(const bf16x8*)&Ps[wid * 16 + l15][ks * 32 + l4 * 8];
#pragma unroll
        for (int n16 = 0; n16 < 2; ++n16) {
            bf16x8 kb = *(const bf16x8*)&kvt[n16 * 16 + l15][ks * 32 + l4 * 8];
            o[n16] = MFMA16(pa, kb, o[n16]);
        }
    }
#pragma unroll
    for (int n16 = 0; n16 < 2; ++n16) {
#pragma unroll
        for (int r = 0; r < 4; ++r) {
            int row = wid * 16 + l4 * 4 + r;
            int n = m0 + row;
            int gy = n >> 5, gx = n & 31;
            int hd = n16 * 16 + l15;
            int py = 2 * h + (hd >> 4), px = hd & 15;
            out[((size_t)b * 512 + gy * 16 + py) * 512 + gx * 16 + px] = o[n16][r] / rs[r];
        }
    }
}

// ---------------------------------------------------------------- launch
extern "C" void kernel_launch(void* const* d_in, const int* in_sizes, int n_in,
                              void* d_out, int out_size, void* d_ws, size_t ws_size,
                              hipStream_t stream) {
    (void)in_sizes; (void)n_in; (void)out_size; (void)ws_size;

    const float* q  = (const float*)d_in[0];
    const float* k  = (const float*)d_in[1];
    const float* v  = (const float*)d_in[2];
    const float* a  = (const float*)d_in[3];
    const float* wq = (const float*)d_in[4];
    const float* bq = (const float*)d_in[5];
    const float* wk = (const float*)d_in[6];
    const float* bk = (const float*)d_in[7];
    const float* wv = (const float*)d_in[8];
    const float* bv = (const float*)d_in[9];
    const float* wa = (const float*)d_in[10];
    const float* ba = (const float*)d_in[11];
    float* out = (float*)d_out;

    char* ws = (char*)d_ws;
    float* pe           = (float*)(ws);                      // 1 MB
    unsigned short* qh  = (unsigned short*)(ws + 1048576);   // 8 MB  (b,h,n,hd)
    unsigned short* kh  = (unsigned short*)(ws + 9437184);   // 8 MB  (b,h,n,hd)
    unsigned short* ah  = (unsigned short*)(ws + 17825792);  // 2 MB  (b,h,n,hd)
    unsigned short* vT  = (unsigned short*)(ws + 19922944);  // 8 MB  (b,h,hd,n)
    unsigned short* kvT = (unsigned short*)(ws + 28311552);  // 2 MB  (b,h,hd,m)
    // total 30,408,704 bytes

    pe_fill<<<1024, 256, 0, stream>>>(pe);

    EmbedArgs Aq = { q, wq, bq, pe, qh, 1024, 10, 32, 5, 512, 0 };
    EmbedArgs Ak = { k, wk, bk, pe, kh, 1024, 10, 32, 5, 512, 0 };
    EmbedArgs Av = { v, wv, bv, pe, vT, 1024, 10, 32, 5, 512, 1 };
    EmbedArgs Aa = { a, wa, ba, pe, ah,  256,  8, 16, 4, 256, 0 };
    embed_all<<<416, 512, 0, stream>>>(Aq, Ak, Av, Aa);

    s2kv_kernel<<<256, 512, 0, stream>>>(ah, kh, vT, kvT);
    qsa_kernel<<<2048, 256, 0, stream>>>(qh, ah, kvT, out);
}